// Round 1
// baseline (244.748 us; speedup 1.0000x reference)
//
#include <hip/hip_runtime.h>

// PCEN: x [32, 256, 4096] fp32. EMA over time per row, then
// out = sqrt(x / (m+eps)^0.98 + 2) - sqrt(2).
//
// Wave-per-row structure: NO barriers, NO LDS, no cross-wave traffic.
// Each 64-lane wave owns one row of 4096. Row is processed as 4 chunks
// of 1024 elements (16 elems = 4 float4 per lane, per-lane contiguous
// time segment). Per chunk:
//   - local EMA scan (zero-init) -> per-lane segment total, coeff A16
//   - 6-step Hillis-Steele wave scan with constexpr coeffs A16^(2^d)
//   - chunk carry folded in via per-lane factor A16^lane (bit-decomposed)
//   - fused epilogue (exp2/log2/sqrt) + coalesced-ish float4 stores
// Chunks are double-buffered in registers: chunk c+1's 4 loads are issued
// before chunk c's scan/epilogue, so HBM latency hides under compute.
// 24+ waves/CU, each with 4 outstanding float4 loads -> latency-bound
// structure of the previous version (2 barrier-lockstep blocks/CU,
// serial 15-step LDS carry) is gone.

constexpr int T_LEN  = 4096;
constexpr int LANES  = 64;
constexpr int QUADS  = 4;                  // float4 per lane per chunk
constexpr int PER_LANE = QUADS * 4;        // 16 elements per lane per chunk
constexpr int CHUNK  = LANES * PER_LANE;   // 1024 elements per chunk
constexpr int CHUNK_F4 = CHUNK / 4;        // 256 float4 per chunk
constexpr int NCHUNK = T_LEN / CHUNK;      // 4
constexpr int WAVES_PER_BLK = 4;
constexpr int NTHR   = LANES * WAVES_PER_BLK;

constexpr float EPSF = 1e-6f;
constexpr float SF   = 0.025f;
constexpr float A1F  = 0.975f;

// exact powers of 0.975 via constexpr repeated squaring
constexpr double dA1    = 0.975;
constexpr double dA2    = dA1 * dA1;
constexpr double dA4    = dA2 * dA2;
constexpr double dA8    = dA4 * dA4;
constexpr double dA16   = dA8 * dA8;      // per-lane segment coeff (16 steps)
constexpr double dA32   = dA16 * dA16;
constexpr double dA64   = dA32 * dA32;
constexpr double dA128  = dA64 * dA64;
constexpr double dA256  = dA128 * dA128;
constexpr double dA512  = dA256 * dA256;
constexpr double dA1024 = dA512 * dA512;  // per-chunk coeff (64 segments x 16)

__global__ __launch_bounds__(NTHR, 6) void pcen_wave_kernel(
    const float* __restrict__ x, float* __restrict__ out, int rows)
{
    const int lane = threadIdx.x & 63;
    const int wave = threadIdx.x >> 6;
    const int row  = blockIdx.x * WAVES_PER_BLK + wave;
    if (row >= rows) return;

    const long long base = (long long)row * T_LEN;
    const float4* __restrict__ px   = (const float4*)(x + base);
    float4* __restrict__       pout = (float4*)(out + base);

    const float cA16  = (float)dA16;
    const float cA32  = (float)dA32;
    const float cA64  = (float)dA64;
    const float cA128 = (float)dA128;
    const float cA256 = (float)dA256;
    const float cA512 = (float)dA512;
    const float cA1024 = (float)dA1024;

    // lane-constant carry factor: A16^lane (exponent = lane, 0..63)
    float flane = 1.0f;
    if (lane & 1)  flane *= cA16;
    if (lane & 2)  flane *= cA32;
    if (lane & 4)  flane *= cA64;
    if (lane & 8)  flane *= cA128;
    if (lane & 16) flane *= cA256;
    if (lane & 32) flane *= cA512;

    const float SQRT_D = 1.41421356237309515f;  // sqrt(2.0)

    // ---- prologue: load chunk 0 (4 independent float4 loads in flight) ----
    float4 buf[QUADS];
    {
        const float4* p = px + lane * QUADS;
#pragma unroll
        for (int j = 0; j < QUADS; ++j) buf[j] = p[j];
    }

    float carry = 0.0f;  // EMA value at end of previous chunk (0 before t=0)

#pragma unroll
    for (int c = 0; c < NCHUNK; ++c) {
        // ---- prefetch next chunk (loads issued before this chunk's compute) ----
        float4 nxt[QUADS];
        if (c < NCHUNK - 1) {
            const float4* p = px + (c + 1) * CHUNK_F4 + lane * QUADS;
#pragma unroll
            for (int j = 0; j < QUADS; ++j) nxt[j] = p[j];
        }

        // ---- local scan (zero init) -> segment total ----
        float m = 0.0f;
#pragma unroll
        for (int j = 0; j < QUADS; ++j) {
            m = fmaf(A1F, m, SF * buf[j].x);
            m = fmaf(A1F, m, SF * buf[j].y);
            m = fmaf(A1F, m, SF * buf[j].z);
            m = fmaf(A1F, m, SF * buf[j].w);
        }
        float Sv = m;  // inclusive local total for this lane's 16-elem segment

        // ---- wave-level inclusive scan, coeff A16^offset ----
        float t;
        t = __shfl_up(Sv, 1,  64); if (lane >= 1)  Sv = fmaf(cA16,  t, Sv);
        t = __shfl_up(Sv, 2,  64); if (lane >= 2)  Sv = fmaf(cA32,  t, Sv);
        t = __shfl_up(Sv, 4,  64); if (lane >= 4)  Sv = fmaf(cA64,  t, Sv);
        t = __shfl_up(Sv, 8,  64); if (lane >= 8)  Sv = fmaf(cA128, t, Sv);
        t = __shfl_up(Sv, 16, 64); if (lane >= 16) Sv = fmaf(cA256, t, Sv);
        t = __shfl_up(Sv, 32, 64); if (lane >= 32) Sv = fmaf(cA512, t, Sv);

        // exclusive prefix (previous lane's inclusive, 0 for lane 0)
        float excl = __shfl_up(Sv, 1, 64);
        if (lane == 0) excl = 0.0f;

        // init m for this lane's segment: local exclusive + A16^lane * carry
        m = fmaf(flane, carry, excl);

        // carry for next chunk: inclusive at lane 63 end + A1024 * old carry
        float last = __shfl(Sv, 63, 64);
        carry = fmaf(cA1024, carry, last);

        // ---- second pass: exact EMA + fused epilogue + store per quad ----
        float4* q = pout + c * CHUNK_F4 + lane * QUADS;
#pragma unroll
        for (int j = 0; j < QUADS; ++j) {
            float4 v = buf[j];
            float4 o;
            m = fmaf(A1F, m, SF * v.x);
            o.x = __builtin_amdgcn_sqrtf(
                      fmaf(v.x, __builtin_amdgcn_exp2f(
                          -0.98f * __builtin_amdgcn_logf(m + EPSF)), 2.0f)) - SQRT_D;
            m = fmaf(A1F, m, SF * v.y);
            o.y = __builtin_amdgcn_sqrtf(
                      fmaf(v.y, __builtin_amdgcn_exp2f(
                          -0.98f * __builtin_amdgcn_logf(m + EPSF)), 2.0f)) - SQRT_D;
            m = fmaf(A1F, m, SF * v.z);
            o.z = __builtin_amdgcn_sqrtf(
                      fmaf(v.z, __builtin_amdgcn_exp2f(
                          -0.98f * __builtin_amdgcn_logf(m + EPSF)), 2.0f)) - SQRT_D;
            m = fmaf(A1F, m, SF * v.w);
            o.w = __builtin_amdgcn_sqrtf(
                      fmaf(v.w, __builtin_amdgcn_exp2f(
                          -0.98f * __builtin_amdgcn_logf(m + EPSF)), 2.0f)) - SQRT_D;
            q[j] = o;
        }

        // rotate double buffer
#pragma unroll
        for (int j = 0; j < QUADS; ++j) buf[j] = nxt[j];
    }
}

extern "C" void kernel_launch(void* const* d_in, const int* in_sizes, int n_in,
                              void* d_out, int out_size, void* d_ws, size_t ws_size,
                              hipStream_t stream) {
    const float* x = (const float*)d_in[0];
    float* out = (float*)d_out;
    const int rows = in_sizes[0] / T_LEN;  // 32*256 = 8192
    const int blocks = (rows + WAVES_PER_BLK - 1) / WAVES_PER_BLK;
    pcen_wave_kernel<<<dim3(blocks), dim3(NTHR), 0, stream>>>(x, out, rows);
}

// Round 2
// 232.432 us; speedup vs baseline: 1.0530x; 1.0530x over previous
//
#include <hip/hip_runtime.h>

// PCEN: x [32, 256, 4096] fp32. EMA over time per row, then
// out = sqrt(x / (m+eps)^0.98 + 2) - sqrt(2).
//
// Wave-per-row, NO barriers, NO LDS, fully COALESCED memory.
// Each 64-lane wave owns one row of 4096. Row = 4 tiles of 1024.
// Each tile = 4 coalesced sub-chunks of 256 elems (lane i holds float4 #i:
// one 1 KB contiguous load/store instruction per sub-chunk -> full 64B
// lines, no write amplification; round-1's per-lane-contiguous layout
// caused +19% WRITE_SIZE RMW and 2.5 TB/s).
// Per sub-chunk: 4-elem local EMA scan (segment coeff A4), 6-step
// Hillis-Steele wave scan (coeffs A4^(2^d)) -- the 4 sub-chunk scans are
// independent (4-way ILP on the shuffle chain); only the per-sub-chunk
// carry FMA (coeff A256) is serial. Tiles are double-buffered in
// registers so the next tile's 4 loads are in flight under this tile's
// scan+epilogue. ~50 VGPR, launch_bounds(256,8) -> 32 waves/CU: the
// whole 8192-row grid is resident in one generation.

constexpr int T_LEN   = 4096;
constexpr int LANES   = 64;
constexpr int SUBS    = 4;                    // sub-chunks per tile
constexpr int TILE    = LANES * 4 * SUBS;     // 1024 elements per tile
constexpr int TILE_F4 = TILE / 4;             // 256 float4
constexpr int NTILE   = T_LEN / TILE;         // 4
constexpr int WAVES_PER_BLK = 4;
constexpr int NTHR    = LANES * WAVES_PER_BLK;

constexpr float EPSF = 1e-6f;
constexpr float SF   = 0.025f;
constexpr float A1F  = 0.975f;

// exact powers of 0.975 via constexpr repeated squaring
constexpr double dA1   = 0.975;
constexpr double dA2   = dA1 * dA1;
constexpr double dA4   = dA2 * dA2;     // per-lane segment coeff (4 steps)
constexpr double dA8   = dA4 * dA4;
constexpr double dA16  = dA8 * dA8;
constexpr double dA32  = dA16 * dA16;
constexpr double dA64  = dA32 * dA32;
constexpr double dA128 = dA64 * dA64;
constexpr double dA256 = dA128 * dA128; // per-sub-chunk coeff (64 lanes x 4)

__global__ __launch_bounds__(NTHR, 8) void pcen_wave_kernel(
    const float* __restrict__ x, float* __restrict__ out, int rows)
{
    const int lane = threadIdx.x & 63;
    const int wave = threadIdx.x >> 6;
    const int row  = blockIdx.x * WAVES_PER_BLK + wave;
    if (row >= rows) return;

    const long long base = (long long)row * T_LEN;
    const float4* __restrict__ px   = (const float4*)(x + base);
    float4* __restrict__       pout = (float4*)(out + base);

    const float cA4   = (float)dA4;
    const float cA8   = (float)dA8;
    const float cA16  = (float)dA16;
    const float cA32  = (float)dA32;
    const float cA64  = (float)dA64;
    const float cA128 = (float)dA128;
    const float cA256 = (float)dA256;

    // lane-constant carry decay: A4^lane (lane's segment starts 4*lane steps in)
    float flane = 1.0f;
    if (lane & 1)  flane *= cA4;
    if (lane & 2)  flane *= cA8;
    if (lane & 4)  flane *= cA16;
    if (lane & 8)  flane *= cA32;
    if (lane & 16) flane *= cA64;
    if (lane & 32) flane *= cA128;

    const float SQRT_D = 1.41421356237309515f;  // sqrt(2.0)

    // ---- prologue: load tile 0 (4 independent coalesced 1KB loads) ----
    float4 buf[SUBS];
#pragma unroll
    for (int j = 0; j < SUBS; ++j) buf[j] = px[j * LANES + lane];

    float carry = 0.0f;  // EMA value at end of previous sub-chunk

#pragma unroll
    for (int t = 0; t < NTILE; ++t) {
        // ---- prefetch next tile ----
        float4 nxt[SUBS];
        if (t < NTILE - 1) {
#pragma unroll
            for (int j = 0; j < SUBS; ++j)
                nxt[j] = px[(t + 1) * TILE_F4 + j * LANES + lane];
        }

        // ---- local 4-elem scans (zero init) -> per-lane segment totals ----
        float Sv[SUBS];
#pragma unroll
        for (int j = 0; j < SUBS; ++j) {
            float m = SF * buf[j].x;
            m = fmaf(A1F, m, SF * buf[j].y);
            m = fmaf(A1F, m, SF * buf[j].z);
            m = fmaf(A1F, m, SF * buf[j].w);
            Sv[j] = m;
        }

        // ---- 4 independent wave scans, coeff A4^offset (4-way ILP) ----
#pragma unroll
        for (int j = 0; j < SUBS; ++j) {
            float tt;
            tt = __shfl_up(Sv[j], 1,  64); if (lane >= 1)  Sv[j] = fmaf(cA4,   tt, Sv[j]);
            tt = __shfl_up(Sv[j], 2,  64); if (lane >= 2)  Sv[j] = fmaf(cA8,   tt, Sv[j]);
            tt = __shfl_up(Sv[j], 4,  64); if (lane >= 4)  Sv[j] = fmaf(cA16,  tt, Sv[j]);
            tt = __shfl_up(Sv[j], 8,  64); if (lane >= 8)  Sv[j] = fmaf(cA32,  tt, Sv[j]);
            tt = __shfl_up(Sv[j], 16, 64); if (lane >= 16) Sv[j] = fmaf(cA64,  tt, Sv[j]);
            tt = __shfl_up(Sv[j], 32, 64); if (lane >= 32) Sv[j] = fmaf(cA128, tt, Sv[j]);
        }

        // ---- per-sub-chunk seed + serial carry chain (cheap FMAs) ----
        float seed[SUBS];
#pragma unroll
        for (int j = 0; j < SUBS; ++j) {
            float excl = __shfl_up(Sv[j], 1, 64);
            if (lane == 0) excl = 0.0f;
            float last = __shfl(Sv[j], 63, 64);
            seed[j] = fmaf(flane, carry, excl);   // m before lane's segment
            carry   = fmaf(cA256, carry, last);   // m at end of sub-chunk
        }

        // ---- epilogue: exact EMA recompute + fused PCEN + coalesced store ----
#pragma unroll
        for (int j = 0; j < SUBS; ++j) {
            float4 v = buf[j];
            float  m = seed[j];
            float4 o;
            m = fmaf(A1F, m, SF * v.x);
            o.x = __builtin_amdgcn_sqrtf(
                      fmaf(v.x, __builtin_amdgcn_exp2f(
                          -0.98f * __builtin_amdgcn_logf(m + EPSF)), 2.0f)) - SQRT_D;
            m = fmaf(A1F, m, SF * v.y);
            o.y = __builtin_amdgcn_sqrtf(
                      fmaf(v.y, __builtin_amdgcn_exp2f(
                          -0.98f * __builtin_amdgcn_logf(m + EPSF)), 2.0f)) - SQRT_D;
            m = fmaf(A1F, m, SF * v.z);
            o.z = __builtin_amdgcn_sqrtf(
                      fmaf(v.z, __builtin_amdgcn_exp2f(
                          -0.98f * __builtin_amdgcn_logf(m + EPSF)), 2.0f)) - SQRT_D;
            m = fmaf(A1F, m, SF * v.w);
            o.w = __builtin_amdgcn_sqrtf(
                      fmaf(v.w, __builtin_amdgcn_exp2f(
                          -0.98f * __builtin_amdgcn_logf(m + EPSF)), 2.0f)) - SQRT_D;
            pout[t * TILE_F4 + j * LANES + lane] = o;
        }

        // rotate double buffer
#pragma unroll
        for (int j = 0; j < SUBS; ++j) buf[j] = nxt[j];
    }
}

extern "C" void kernel_launch(void* const* d_in, const int* in_sizes, int n_in,
                              void* d_out, int out_size, void* d_ws, size_t ws_size,
                              hipStream_t stream) {
    const float* x = (const float*)d_in[0];
    float* out = (float*)d_out;
    const int rows = in_sizes[0] / T_LEN;  // 32*256 = 8192
    const int blocks = (rows + WAVES_PER_BLK - 1) / WAVES_PER_BLK;
    pcen_wave_kernel<<<dim3(blocks), dim3(NTHR), 0, stream>>>(x, out, rows);
}